// Round 5
// baseline (256.503 us; speedup 1.0000x reference)
//
#include <hip/hip_runtime.h>
#include <hip/hip_bf16.h>

#define B_      512
#define NI      1152
#define NO      10
#define BT      16
#define NBT     32            // B_/BT
#define NC      48            // chunks
#define NCH     24            // NI/NC
#define NGRP    6             // NCH/4 groups of 4 n per chunk

typedef __attribute__((ext_vector_type(8))) short bf16x8;
typedef __attribute__((ext_vector_type(4))) float f32x4;
typedef __attribute__((ext_vector_type(8))) unsigned short u16x8;

// workspace (f32 / ushort counts)
#define SPART_F32  ((size_t)NC * NBT * NO * 256)   // 3,932,160 f32 (15.7 MB)
#define OUTSUM_F32 ((size_t)NBT * NO * 256)        //    81,920 f32 (0.33 MB)
// wb: NC*NGRP*NO*512 ushorts = 2.95 MB; total ws ~= 19.0 MB

__device__ inline unsigned short f2bf(float f) {
    __hip_bfloat16 h = __float2bfloat16(f);
    return *reinterpret_cast<unsigned short*>(&h);
}

// w[o][n][d][j] f32 -> wb granule[((nc*NGRP+g)*NO+o)*64 + nn*16 + d] of 8 bf16
__global__ __launch_bounds__(256) void cvt_w(
    const float* __restrict__ w, unsigned short* __restrict__ wb)
{
    const int t = blockIdx.x * 256 + threadIdx.x;       // 184,320 threads
    float4 v0 = *reinterpret_cast<const float4*>(w + (size_t)t * 8);
    float4 v1 = *reinterpret_cast<const float4*>(w + (size_t)t * 8 + 4);
    u16x8 u = { f2bf(v0.x), f2bf(v0.y), f2bf(v0.z), f2bf(v0.w),
                f2bf(v1.x), f2bf(v1.y), f2bf(v1.z), f2bf(v1.w) };
    const int o = t / (NI * 16);
    const int rem = t - o * (NI * 16);
    const int n = rem >> 4, d = rem & 15;
    const int nc = n / NCH, nl = n - nc * NCH;
    const int g = nl >> 2, nn = nl & 3;
    size_t gr = (((size_t)nc * NGRP + g) * NO + o) * 64 + nn * 16 + d;
    *reinterpret_cast<u16x8*>(wb + gr * 8) = u;
}

// One routing iteration. Block = (btg pair of b-tiles) x (nc chunk).
// Wave w: bt = btg*2 + (w>>1), groups g = (w&1)*3 .. +2.
// Lane (b16,hi): A = W[o, 4g+hi, d=b16, :], B = x[b16, 4g+hi, :] (bf16).
template<bool UNIFORM>
__global__ __launch_bounds__(256, 3) void caps_iter(
    const float* __restrict__ x,        // [B][NI][8] f32
    const unsigned short* __restrict__ wb,
    const float* __restrict__ outsum,   // [bt*10+o][64][4] lane-major f32
    float* __restrict__ s_part)         // [nc][bt*10+o][64][4] f32
{
    __shared__ f32x4 red[4][NO * 64];   // 40,960 B (epilogue only)

    const int tid = threadIdx.x;
    const int w   = tid >> 6;
    const int l   = tid & 63;
    const int b16 = l & 15;
    const int hi  = l >> 4;
    const int btg = blockIdx.x / NC;    // 0..15
    const int nc  = blockIdx.x % NC;
    const int bt  = btg * 2 + (w >> 1); // wave's b-tile
    const int gs  = (w & 1) * 3;        // wave's group offset

    f32x4 outf[NO];
    if constexpr (!UNIFORM) {
        #pragma unroll
        for (int o = 0; o < NO; ++o)
            outf[o] = *reinterpret_cast<const f32x4*>(
                outsum + (((size_t)bt * NO + o) * 64 + l) * 4);
    }

    f32x4 sacc[NO];
    #pragma unroll
    for (int o = 0; o < NO; ++o) sacc[o] = (f32x4){0.f, 0.f, 0.f, 0.f};

    const unsigned short* wbase = wb + ((size_t)nc * NGRP * NO) * 512 + l * 8;
    const float* xrow = x + ((size_t)(bt * BT + b16) * NI + nc * NCH) * 8;

    #pragma unroll 1
    for (int gi = 0; gi < 3; ++gi) {
        const int g = gs + gi;

        // x[b16, nc*24 + 4g + hi, :] f32 -> bf16 (nt: pure stream)
        const float* xp = xrow + (4 * g + hi) * 8;
        f32x4 xa = __builtin_nontemporal_load(reinterpret_cast<const f32x4*>(xp));
        f32x4 xc = __builtin_nontemporal_load(reinterpret_cast<const f32x4*>(xp + 4));
        u16x8 xu = { f2bf(xa[0]), f2bf(xa[1]), f2bf(xa[2]), f2bf(xa[3]),
                     f2bf(xc[0]), f2bf(xc[1]), f2bf(xc[2]), f2bf(xc[3]) };
        bf16x8 bv4 = *reinterpret_cast<bf16x8*>(&xu);

        bf16x8 av4[NO];
        #pragma unroll
        for (int o = 0; o < NO; ++o)
            av4[o] = *reinterpret_cast<const bf16x8*>(
                wbase + ((size_t)(g * NO + o)) * 512);

        if constexpr (UNIFORM) {
            #pragma unroll
            for (int o = 0; o < NO; ++o)
                sacc[o] = __builtin_amdgcn_mfma_f32_16x16x32_bf16(
                    av4[o], bv4, sacc[o], 0, 0, 0);
        } else {
            #pragma unroll
            for (int t = 0; t < 4; ++t) {
                bf16x8 bvt = (hi == t) ? bv4 : (bf16x8){0,0,0,0,0,0,0,0};
                float p[NO];
                #pragma unroll
                for (int o = 0; o < NO; ++o) {
                    f32x4 xh = __builtin_amdgcn_mfma_f32_16x16x32_bf16(
                        av4[o], bvt, (f32x4){0.f, 0.f, 0.f, 0.f}, 0, 0, 0);
                    float pp = outf[o][0] * xh[0];
                    pp = fmaf(outf[o][1], xh[1], pp);
                    pp = fmaf(outf[o][2], xh[2], pp);
                    pp = fmaf(outf[o][3], xh[3], pp);
                    pp += __shfl_xor(pp, 16, 64);
                    pp += __shfl_xor(pp, 32, 64);
                    p[o] = pp;
                }
                float sum = 0.f;
                #pragma unroll
                for (int o = 0; o < NO; ++o) { p[o] = __expf(p[o]); sum += p[o]; }
                const float rs = __builtin_amdgcn_rcpf(sum);
                #pragma unroll
                for (int o = 0; o < NO; ++o) {
                    const float cc = p[o] * rs;
                    f32x4 xh = __builtin_amdgcn_mfma_f32_16x16x32_bf16(
                        av4[o], bvt, (f32x4){0.f, 0.f, 0.f, 0.f}, 0, 0, 0);
                    sacc[o][0] = fmaf(cc, xh[0], sacc[o][0]);
                    sacc[o][1] = fmaf(cc, xh[1], sacc[o][1]);
                    sacc[o][2] = fmaf(cc, xh[2], sacc[o][2]);
                    sacc[o][3] = fmaf(cc, xh[3], sacc[o][3]);
                }
            }
        }
    }

    // pair-reduce the two waves sharing each bt, then nt-store s_part
    const float sc = UNIFORM ? 0.1f : 1.0f;
    #pragma unroll
    for (int o = 0; o < NO; ++o) {
        f32x4 v = { sacc[o][0] * sc, sacc[o][1] * sc,
                    sacc[o][2] * sc, sacc[o][3] * sc };
        red[w][o * 64 + l] = v;
    }
    __syncthreads();
    float* base = s_part + (size_t)nc * (NBT * NO * 256);
    for (int idx = tid; idx < 2 * NO * 64; idx += 256) {   // 1280 granules
        const int p   = idx / (NO * 64);                   // pair 0/1
        const int rem = idx - p * (NO * 64);               // o*64 + l
        f32x4 a = red[2 * p][rem], b = red[2 * p + 1][rem];
        f32x4 s = { a[0] + b[0], a[1] + b[1], a[2] + b[2], a[3] + b[3] };
        const int btp = btg * 2 + p;
        __builtin_nontemporal_store(s, reinterpret_cast<f32x4*>(
            base + ((size_t)(btp * NO * 64) + rem) * 4));
    }
}

// Reduce chunks + squash. Block bo = bt*10+o; thread t = l*4+q, d = hi*4+q.
template<int MODE>
__global__ __launch_bounds__(256) void caps_squash(
    const float* __restrict__ s_part,
    float* __restrict__ outsum,
    float* __restrict__ dout)
{
    __shared__ float sq[256];
    const int bo = blockIdx.x;
    const int t  = threadIdx.x;

    float s = 0.f;
    #pragma unroll
    for (int nc = 0; nc < NC; ++nc)
        s += __builtin_nontemporal_load(
            s_part + ((size_t)nc * NBT * NO + bo) * 256 + t);

    float n2 = s * s;
    n2 += __shfl_xor(n2, 1, 64);
    n2 += __shfl_xor(n2, 2, 64);       // q-group reduced
    sq[t] = n2;
    __syncthreads();
    const int base = t & 63;
    n2 = (sq[base] + sq[64 + base]) + (sq[128 + base] + sq[192 + base]);

    const float norm  = sqrtf(n2);
    const float scale = n2 / ((1.f + n2) * (norm + 1e-8f));
    const float v = scale * s;

    if constexpr (MODE == 0) {
        outsum[(size_t)bo * 256 + t] = v;
    } else if constexpr (MODE == 1) {
        outsum[(size_t)bo * 256 + t] += v;
    } else {
        const int bt = bo / NO, o = bo - bt * NO;
        const int b16 = (t >> 2) & 15, hi = t >> 6, q = t & 3;
        dout[((size_t)(bt * BT + b16) * NO + o) * 16 + hi * 4 + q] = v;
    }
}

extern "C" void kernel_launch(void* const* d_in, const int* in_sizes, int n_in,
                              void* d_out, int out_size, void* d_ws, size_t ws_size,
                              hipStream_t stream) {
    const float* x = (const float*)d_in[0];   // [512][1152][8]
    const float* w = (const float*)d_in[1];   // [10][1152][16][8]
    float* out = (float*)d_out;               // [512][10][16]

    float* s_part          = (float*)d_ws;
    float* outsum          = s_part + SPART_F32;
    unsigned short* wb     = (unsigned short*)(outsum + OUTSUM_F32);

    cvt_w<<<dim3(720), dim3(256), 0, stream>>>(w, wb);

    dim3 gI(16 * NC), bI(256);                // 768 blocks = 3/CU
    dim3 gS(NBT * NO), bS(256);               // 320 blocks

    caps_iter<true ><<<gI, bI, 0, stream>>>(x, wb, nullptr, s_part);
    caps_squash<0><<<gS, bS, 0, stream>>>(s_part, outsum, nullptr);
    caps_iter<false><<<gI, bI, 0, stream>>>(x, wb, outsum, s_part);
    caps_squash<1><<<gS, bS, 0, stream>>>(s_part, outsum, nullptr);
    caps_iter<false><<<gI, bI, 0, stream>>>(x, wb, outsum, s_part);
    caps_squash<2><<<gS, bS, 0, stream>>>(s_part, nullptr, out);
}

// Round 6
// 212.510 us; speedup vs baseline: 1.2070x; 1.2070x over previous
//
#include <hip/hip_runtime.h>
#include <hip/hip_bf16.h>
#include <hip/hip_fp16.h>

#define B_    512
#define NI    1152
#define NO    10
#define BT    16
#define NBT   32           // B_/BT
#define NC    96           // chunks
#define NCH   12           // n per chunk
#define NGRP  3            // groups of 4 n per chunk

typedef __attribute__((ext_vector_type(8))) short bf16x8;
typedef __attribute__((ext_vector_type(4))) float f32x4;
typedef __attribute__((ext_vector_type(8))) unsigned short u16x8;

// workspace element counts
#define SPART_H    ((size_t)NC * NBT * NO * 256)    // 7,864,320 halfs (15.7 MB)
#define OUTSUM_F32 ((size_t)NBT * NO * 256)         //    81,920 f32  (0.33 MB)
#define XB_US      ((size_t)NC * 8 * 4 * NGRP * 512)// 4,718,592 us   (9.44 MB)
// wb: NC*NGRP*NO*512 = 1,474,560 us (2.95 MB); total ws ~= 28.4 MB

__device__ inline unsigned short f2bf(float f) {
    __hip_bfloat16 h = __float2bfloat16(f);
    return *reinterpret_cast<unsigned short*>(&h);
}

__device__ inline void gld_lds16(const void* g, void* lds) {
    __builtin_amdgcn_global_load_lds(
        (const __attribute__((address_space(1))) void*)g,
        (__attribute__((address_space(3))) void*)lds, 16, 0, 0);
}

// x[b][n][j] f32 -> xb granule-set gs=((nc*8+btg)*4+wq)*3+g, lane nn*16+bl
__global__ __launch_bounds__(256) void cvt_x(
    const float* __restrict__ x, unsigned short* __restrict__ xb)
{
    const int t = blockIdx.x * 256 + threadIdx.x;     // 589,824 threads
    float4 v0 = *reinterpret_cast<const float4*>(x + (size_t)t * 8);
    float4 v1 = *reinterpret_cast<const float4*>(x + (size_t)t * 8 + 4);
    u16x8 u = { f2bf(v0.x), f2bf(v0.y), f2bf(v0.z), f2bf(v0.w),
                f2bf(v1.x), f2bf(v1.y), f2bf(v1.z), f2bf(v1.w) };
    const int b = t / NI, n = t - b * NI;
    const int nc = n / NCH, nl = n - nc * NCH;
    const int g = nl >> 2, nn = nl & 3;
    const int btg = b >> 6, wq = (b >> 4) & 3, bl = b & 15;
    size_t gs = (((size_t)nc * 8 + btg) * 4 + wq) * NGRP + g;
    *reinterpret_cast<u16x8*>(xb + gs * 512 + (nn * 16 + bl) * 8) = u;
}

// w[o][n][d][j] f32 -> wb granule-set gs=(nc*3+g)*10+o, lane nn*16+d
__global__ __launch_bounds__(256) void cvt_w(
    const float* __restrict__ w, unsigned short* __restrict__ wb)
{
    const int t = blockIdx.x * 256 + threadIdx.x;     // 184,320 threads
    float4 v0 = *reinterpret_cast<const float4*>(w + (size_t)t * 8);
    float4 v1 = *reinterpret_cast<const float4*>(w + (size_t)t * 8 + 4);
    u16x8 u = { f2bf(v0.x), f2bf(v0.y), f2bf(v0.z), f2bf(v0.w),
                f2bf(v1.x), f2bf(v1.y), f2bf(v1.z), f2bf(v1.w) };
    const int o = t / (NI * 16);
    const int rem = t - o * (NI * 16);
    const int n = rem >> 4, d = rem & 15;
    const int nc = n / NCH, nl = n - nc * NCH;
    const int g = nl >> 2, nn = nl & 3;
    size_t gs = ((size_t)nc * NGRP + g) * NO + o;
    *reinterpret_cast<u16x8*>(wb + gs * 512 + (nn * 16 + d) * 8) = u;
}

// One routing iteration. Block = (btg quad of b-tiles) x (nc chunk); wave w
// owns bt = btg*4+w. Whole chunk staged to LDS once; ONE barrier; direct
// per-wave global store of partials (fp16).
template<bool UNIFORM>
__global__ __launch_bounds__(256, 3) void caps_iter(
    const unsigned short* __restrict__ xb,
    const unsigned short* __restrict__ wb,
    const float* __restrict__ outsum,   // [bt*10+o][64][4] lane-major f32
    unsigned short* __restrict__ s_part)// [nc][bt*10+o][64][4] fp16
{
    __shared__ unsigned short lds[21504];   // 43,008 B: xs 12,288 + wsh 30,720

    const int tid = threadIdx.x;
    const int w   = tid >> 6;
    const int l   = tid & 63;
    const int hi  = l >> 4;
    const int blk = blockIdx.x;
    const int xcd = blk & 7, i = blk >> 3;  // XCD-aware: same xcd -> same nc range
    const int nc  = xcd * 12 + (i % 12);
    const int btg = i / 12;                 // 0..7
    const int bt  = btg * 4 + w;

    // stage x (12 granule-sets) + W (30 granule-sets), contiguous 16B loads
    const unsigned short* xsrc = xb + ((size_t)nc * 8 + btg) * (4 * NGRP * 512);
    for (int g = tid; g < 768; g += 256)
        gld_lds16(xsrc + g * 8, (char*)lds + g * 16);
    const unsigned short* wsrc = wb + (size_t)nc * (NGRP * NO * 512);
    for (int g = tid; g < 1920; g += 256)
        gld_lds16(wsrc + g * 8, (char*)lds + 12288 + g * 16);

    f32x4 outf[NO];
    if constexpr (!UNIFORM) {
        #pragma unroll
        for (int o = 0; o < NO; ++o)
            outf[o] = *reinterpret_cast<const f32x4*>(
                outsum + (((size_t)bt * NO + o) * 64 + l) * 4);
    }

    f32x4 sacc[NO];
    #pragma unroll
    for (int o = 0; o < NO; ++o) sacc[o] = (f32x4){0.f, 0.f, 0.f, 0.f};

    asm volatile("s_waitcnt vmcnt(0)" ::: "memory");
    __syncthreads();

    #pragma unroll 1
    for (int gi = 0; gi < NGRP; ++gi) {
        bf16x8 bv4 = *reinterpret_cast<const bf16x8*>(
            &lds[((w * NGRP + gi) * 64 + l) * 8]);
        bf16x8 av4[NO];
        #pragma unroll
        for (int o = 0; o < NO; ++o)
            av4[o] = *reinterpret_cast<const bf16x8*>(
                &lds[6144 + ((gi * NO + o) * 64 + l) * 8]);

        if constexpr (UNIFORM) {
            #pragma unroll
            for (int o = 0; o < NO; ++o)
                sacc[o] = __builtin_amdgcn_mfma_f32_16x16x32_bf16(
                    av4[o], bv4, sacc[o], 0, 0, 0);
        } else {
            #pragma unroll
            for (int t = 0; t < 4; ++t) {
                bf16x8 bvt = (hi == t) ? bv4 : (bf16x8){0,0,0,0,0,0,0,0};
                float p[NO];
                #pragma unroll
                for (int o = 0; o < NO; ++o) {
                    f32x4 xh = __builtin_amdgcn_mfma_f32_16x16x32_bf16(
                        av4[o], bvt, (f32x4){0.f, 0.f, 0.f, 0.f}, 0, 0, 0);
                    float pp = outf[o][0] * xh[0];
                    pp = fmaf(outf[o][1], xh[1], pp);
                    pp = fmaf(outf[o][2], xh[2], pp);
                    pp = fmaf(outf[o][3], xh[3], pp);
                    pp += __shfl_xor(pp, 16, 64);
                    pp += __shfl_xor(pp, 32, 64);
                    p[o] = pp;
                }
                float sum = 0.f;
                #pragma unroll
                for (int o = 0; o < NO; ++o) { p[o] = __expf(p[o]); sum += p[o]; }
                const float rs = __builtin_amdgcn_rcpf(sum);
                #pragma unroll
                for (int o = 0; o < NO; ++o) {
                    const float cc = p[o] * rs;
                    f32x4 xh = __builtin_amdgcn_mfma_f32_16x16x32_bf16(
                        av4[o], bvt, (f32x4){0.f, 0.f, 0.f, 0.f}, 0, 0, 0);
                    sacc[o][0] = fmaf(cc, xh[0], sacc[o][0]);
                    sacc[o][1] = fmaf(cc, xh[1], sacc[o][1]);
                    sacc[o][2] = fmaf(cc, xh[2], sacc[o][2]);
                    sacc[o][3] = fmaf(cc, xh[3], sacc[o][3]);
                }
            }
        }
    }

    // direct per-wave store: fp16 partials, 8B/lane, coalesced
    const float sc = UNIFORM ? 0.1f : 1.0f;
    #pragma unroll
    for (int o = 0; o < NO; ++o) {
        __half2 h01 = __floats2half2_rn(sacc[o][0] * sc, sacc[o][1] * sc);
        __half2 h23 = __floats2half2_rn(sacc[o][2] * sc, sacc[o][3] * sc);
        uint2 pk = { *reinterpret_cast<unsigned int*>(&h01),
                     *reinterpret_cast<unsigned int*>(&h23) };
        *reinterpret_cast<uint2*>(
            s_part + ((((size_t)nc * NBT + bt) * NO + o) * 64 + l) * 4) = pk;
    }
}

// Reduce chunks + squash. Block bo = bt*10+o; thread t: l=t>>2, q=t&3, d=hi*4+q.
template<int MODE>
__global__ __launch_bounds__(256) void caps_squash(
    const unsigned short* __restrict__ s_part,
    float* __restrict__ outsum,
    float* __restrict__ dout)
{
    __shared__ float sq[256];
    const int bo = blockIdx.x;
    const int t  = threadIdx.x;

    float s = 0.f;
    #pragma unroll 4
    for (int nc = 0; nc < NC; ++nc) {
        __half h = *reinterpret_cast<const __half*>(
            s_part + ((size_t)nc * NBT * NO + bo) * 256 + t);
        s += __half2float(h);
    }

    float n2 = s * s;
    n2 += __shfl_xor(n2, 1, 64);
    n2 += __shfl_xor(n2, 2, 64);       // q-group reduced
    sq[t] = n2;
    __syncthreads();
    const int base = t & 63;
    n2 = (sq[base] + sq[64 + base]) + (sq[128 + base] + sq[192 + base]);

    const float norm  = sqrtf(n2);
    const float scale = n2 / ((1.f + n2) * (norm + 1e-8f));
    const float v = scale * s;

    if constexpr (MODE == 0) {
        outsum[(size_t)bo * 256 + t] = v;
    } else if constexpr (MODE == 1) {
        outsum[(size_t)bo * 256 + t] += v;
    } else {
        const int bt = bo / NO, o = bo - bt * NO;
        const int b16 = (t >> 2) & 15, hi = t >> 6, q = t & 3;
        dout[((size_t)(bt * BT + b16) * NO + o) * 16 + hi * 4 + q] = v;
    }
}

extern "C" void kernel_launch(void* const* d_in, const int* in_sizes, int n_in,
                              void* d_out, int out_size, void* d_ws, size_t ws_size,
                              hipStream_t stream) {
    const float* x = (const float*)d_in[0];   // [512][1152][8]
    const float* w = (const float*)d_in[1];   // [10][1152][16][8]
    float* out = (float*)d_out;               // [512][10][16]

    unsigned short* s_part = (unsigned short*)d_ws;
    float*          outsum = (float*)(s_part + SPART_H);
    unsigned short* xb     = (unsigned short*)(outsum + OUTSUM_F32);
    unsigned short* wb     = xb + XB_US;

    cvt_x<<<dim3(2304), dim3(256), 0, stream>>>(x, xb);
    cvt_w<<<dim3(720),  dim3(256), 0, stream>>>(w, wb);

    dim3 gI(8 * NC), bI(256);                 // 768 blocks = 3/CU
    dim3 gS(NBT * NO), bS(256);               // 320 blocks

    caps_iter<true ><<<gI, bI, 0, stream>>>(xb, wb, nullptr, s_part);
    caps_squash<0><<<gS, bS, 0, stream>>>(s_part, outsum, nullptr);
    caps_iter<false><<<gI, bI, 0, stream>>>(xb, wb, outsum, s_part);
    caps_squash<1><<<gS, bS, 0, stream>>>(s_part, outsum, nullptr);
    caps_iter<false><<<gI, bI, 0, stream>>>(xb, wb, outsum, s_part);
    caps_squash<2><<<gS, bS, 0, stream>>>(s_part, nullptr, out);
}

// Round 7
// 81.987 us; speedup vs baseline: 3.1286x; 2.5920x over previous
//
#include <hip/hip_runtime.h>
#include <hip/hip_bf16.h>

#define B_    512
#define NI    1152
#define NO    10
#define BT    16
#define NBT   32           // B_/BT
#define NC    24           // s_part chunks (8 XCD x 3)
#define NCH   48           // n per chunk
#define RNDS  3
#define RN    16           // n per staged round

typedef __attribute__((ext_vector_type(8))) short bf16x8;
typedef __attribute__((ext_vector_type(4))) float f32x4;
typedef __attribute__((ext_vector_type(8))) unsigned short u16x8;

// workspace element counts
#define SPART_F32  ((size_t)NC * NBT * NO * 256)     // 1,966,080 f32 (7.86 MB)
#define OUTSUM_F32 ((size_t)NBT * NO * 256)          //    81,920 f32 (0.33 MB)
#define XB_US      ((size_t)NBT * NC * RNDS * 2048)  // 4,718,592 us  (9.44 MB)
#define WB_US      ((size_t)NC * RNDS * 24576)       // 1,769,472 us  (3.54 MB)

__device__ inline unsigned short f2bf(float f) {
    __hip_bfloat16 h = __float2bfloat16(f);
    return *reinterpret_cast<unsigned short*>(&h);
}

__device__ inline void gld_lds16(const void* g, void* lds) {
    __builtin_amdgcn_global_load_lds(
        (const __attribute__((address_space(1))) void*)g,
        (__attribute__((address_space(3))) void*)lds, 16, 0, 0);
}

// x[b][n][8j] f32 -> xb round-image: [(bt*NC+nc)*3+r][nl*128 + bl*8] bf16
// (per-(bt,nc,r) 4KB block == exact LDS image)
__global__ __launch_bounds__(256) void cvt_x(
    const float* __restrict__ x, unsigned short* __restrict__ xb)
{
    const int t  = blockIdx.x * 256 + threadIdx.x;   // 589,824 granules
    const int nl = t & 15;
    const int bl = (t >> 4) & 15;
    const int rest = t >> 8;                         // (bt*NC+nc)*3+r
    const int r  = rest % 3;
    const int bc = rest / 3;
    const int nc = bc % NC, bt = bc / NC;
    const int b  = bt * BT + bl;
    const int n  = nc * NCH + r * RN + nl;
    const float* src = x + ((size_t)b * NI + n) * 8;
    float4 v0 = *reinterpret_cast<const float4*>(src);
    float4 v1 = *reinterpret_cast<const float4*>(src + 4);
    u16x8 u = { f2bf(v0.x), f2bf(v0.y), f2bf(v0.z), f2bf(v0.w),
                f2bf(v1.x), f2bf(v1.y), f2bf(v1.z), f2bf(v1.w) };
    *reinterpret_cast<u16x8*>(xb + (size_t)rest * 2048 + nl * 128 + bl * 8) = u;
}

// w[o][n][d][8j] f32 -> wb round-image: [(nc*3+r)*24576 + (nl*3+oq)*512 +
// (hi*16+d)*8] bf16, where the A-granule (n,oq) k-block hi holds o=4*oq+hi
// (zero for o>=10). Per-(nc,r) 48KB block == exact LDS image.
__global__ __launch_bounds__(256) void cvt_w(
    const float* __restrict__ w, unsigned short* __restrict__ wb)
{
    const int t  = blockIdx.x * 256 + threadIdx.x;   // 221,184 granules
    const int d  = t & 15;
    const int hi = (t >> 4) & 3;
    const int oq = (t >> 6) % 3;
    const int rest = t / 192;
    const int nl = rest % RN;
    const int r  = (rest / RN) % 3;
    const int nc = rest / (RN * 3);
    const int o  = oq * 4 + hi;
    const int n  = nc * NCH + r * RN + nl;
    u16x8 u = {0,0,0,0,0,0,0,0};
    if (o < NO) {
        const float* src = w + ((size_t)o * NI + n) * 128 + d * 8;
        float4 v0 = *reinterpret_cast<const float4*>(src);
        float4 v1 = *reinterpret_cast<const float4*>(src + 4);
        u = (u16x8){ f2bf(v0.x), f2bf(v0.y), f2bf(v0.z), f2bf(v0.w),
                     f2bf(v1.x), f2bf(v1.y), f2bf(v1.z), f2bf(v1.w) };
    }
    *reinterpret_cast<u16x8*>(
        wb + ((size_t)nc * 3 + r) * 24576 + (nl * 3 + oq) * 512
           + (hi * 16 + d) * 8) = u;
}

// One routing iteration. Block = bt x nc; 3 staged rounds of 16 n; wave w
// owns round-local n = w*4+i. A = o-quad W granule, B = x broadcast masked
// to k-block t' -> xh for o = 4*oq + t'. Everything conflict-free.
template<bool UNIFORM>
__global__ __launch_bounds__(256, 3) void caps_iter(
    const unsigned short* __restrict__ xb,
    const unsigned short* __restrict__ wb,
    const float* __restrict__ outsum,    // [bt*10+o][64][4] lane-major f32
    float* __restrict__ s_part)          // [nc][bt][o][64][4] f32
{
    __shared__ unsigned short lds[26624];   // W 24576 us | x 2048 us (53,248 B)

    const int tid = threadIdx.x;
    const int w   = tid >> 6;
    const int l   = tid & 63;
    const int b16 = l & 15;
    const int hi  = l >> 4;
    const int blk = blockIdx.x;
    const int xcd = blk & 7, idx = blk >> 3;      // 96 blocks per XCD
    const int nc  = xcd * 3 + (idx >> 5);         // XCD owns 3 chunks
    const int bt  = idx & 31;

    f32x4 outf[NO];
    if constexpr (!UNIFORM) {
        #pragma unroll
        for (int o = 0; o < NO; ++o)
            outf[o] = *reinterpret_cast<const f32x4*>(
                outsum + (((size_t)bt * NO + o) * 64 + l) * 4);
    }

    f32x4 sacc[NO];
    #pragma unroll
    for (int o = 0; o < NO; ++o) sacc[o] = (f32x4){0.f, 0.f, 0.f, 0.f};

    for (int r = 0; r < RNDS; ++r) {
        if (r) __syncthreads();   // prev round's LDS reads done before overwrite
        const unsigned short* wsrc = wb + ((size_t)nc * 3 + r) * 24576;
        #pragma unroll
        for (int k = 0; k < 12; ++k)
            gld_lds16(wsrc + (k * 256 + tid) * 8, (char*)lds + (k * 256 + tid) * 16);
        const unsigned short* xsrc = xb + (((size_t)bt * NC + nc) * 3 + r) * 2048;
        gld_lds16(xsrc + tid * 8, (char*)lds + 49152 + tid * 16);
        asm volatile("s_waitcnt vmcnt(0)" ::: "memory");
        __syncthreads();

        #pragma unroll 1
        for (int i = 0; i < 4; ++i) {
            const int nl = w * 4 + i;
            // x[b16, n] broadcast to all k-groups, then mask per k-block
            bf16x8 bv = *reinterpret_cast<const bf16x8*>(
                &lds[24576 + nl * 128 + b16 * 8]);
            bf16x8 bvt[4];
            #pragma unroll
            for (int t = 0; t < 4; ++t)
                bvt[t] = (hi == t) ? bv : (bf16x8){0,0,0,0,0,0,0,0};

            if constexpr (UNIFORM) {
                #pragma unroll
                for (int oq = 0; oq < 3; ++oq) {
                    bf16x8 av = *reinterpret_cast<const bf16x8*>(
                        &lds[(nl * 3 + oq) * 512 + l * 8]);
                    const int tmax = (oq < 2) ? 4 : 2;
                    #pragma unroll
                    for (int t = 0; t < tmax; ++t)
                        sacc[oq * 4 + t] = __builtin_amdgcn_mfma_f32_16x16x32_bf16(
                            av, bvt[t], sacc[oq * 4 + t], 0, 0, 0);
                }
            } else {
                float lg[NO];
                #pragma unroll
                for (int oq = 0; oq < 3; ++oq) {
                    bf16x8 av = *reinterpret_cast<const bf16x8*>(
                        &lds[(nl * 3 + oq) * 512 + l * 8]);
                    const int tmax = (oq < 2) ? 4 : 2;
                    #pragma unroll
                    for (int t = 0; t < tmax; ++t) {
                        f32x4 xh = __builtin_amdgcn_mfma_f32_16x16x32_bf16(
                            av, bvt[t], (f32x4){0.f, 0.f, 0.f, 0.f}, 0, 0, 0);
                        const int o = oq * 4 + t;
                        float pp = outf[o][0] * xh[0];
                        pp = fmaf(outf[o][1], xh[1], pp);
                        pp = fmaf(outf[o][2], xh[2], pp);
                        pp = fmaf(outf[o][3], xh[3], pp);
                        pp += __shfl_xor(pp, 16, 64);
                        pp += __shfl_xor(pp, 32, 64);
                        lg[o] = pp;
                    }
                }
                float sum = 0.f;
                #pragma unroll
                for (int o = 0; o < NO; ++o) { lg[o] = __expf(lg[o]); sum += lg[o]; }
                const float rs = __builtin_amdgcn_rcpf(sum);
                #pragma unroll
                for (int oq = 0; oq < 3; ++oq) {
                    bf16x8 av = *reinterpret_cast<const bf16x8*>(
                        &lds[(nl * 3 + oq) * 512 + l * 8]);
                    const int tmax = (oq < 2) ? 4 : 2;
                    #pragma unroll
                    for (int t = 0; t < tmax; ++t) {
                        f32x4 xh = __builtin_amdgcn_mfma_f32_16x16x32_bf16(
                            av, bvt[t], (f32x4){0.f, 0.f, 0.f, 0.f}, 0, 0, 0);
                        const int o = oq * 4 + t;
                        const float cc = lg[o] * rs;
                        sacc[o][0] = fmaf(cc, xh[0], sacc[o][0]);
                        sacc[o][1] = fmaf(cc, xh[1], sacc[o][1]);
                        sacc[o][2] = fmaf(cc, xh[2], sacc[o][2]);
                        sacc[o][3] = fmaf(cc, xh[3], sacc[o][3]);
                    }
                }
            }
        }
    }

    // cross-wave reduce via lane-major LDS (conflict-free), coalesced store
    __syncthreads();
    const float sc = UNIFORM ? 0.1f : 1.0f;
    f32x4* red = reinterpret_cast<f32x4*>(lds);
    #pragma unroll
    for (int o = 0; o < NO; ++o)
        red[w * 640 + o * 64 + l] =
            (f32x4){sacc[o][0] * sc, sacc[o][1] * sc,
                    sacc[o][2] * sc, sacc[o][3] * sc};
    __syncthreads();
    float* base = s_part + ((size_t)nc * NBT + bt) * 2560;
    for (int g = tid; g < 640; g += 256) {
        f32x4 a0 = red[g], a1 = red[640 + g], a2 = red[1280 + g], a3 = red[1920 + g];
        f32x4 s;
        #pragma unroll
        for (int q = 0; q < 4; ++q) s[q] = (a0[q] + a1[q]) + (a2[q] + a3[q]);
        *reinterpret_cast<f32x4*>(base + (size_t)g * 4) = s;
    }
}

// Reduce chunks + squash. Block bo = bt*10+o; thread t: l=t>>2, q=t&3.
template<int MODE>
__global__ __launch_bounds__(256) void caps_squash(
    const float* __restrict__ s_part,
    float* __restrict__ outsum,
    float* __restrict__ dout)
{
    __shared__ float sq[256];
    const int bo = blockIdx.x;
    const int t  = threadIdx.x;

    float s = 0.f;
    #pragma unroll
    for (int nc = 0; nc < NC; ++nc)
        s += s_part[((size_t)nc * NBT * NO + bo) * 256 + t];

    float n2 = s * s;
    n2 += __shfl_xor(n2, 1, 64);
    n2 += __shfl_xor(n2, 2, 64);       // q-pair reduced
    sq[t] = n2;
    __syncthreads();
    const int base = t & 63;
    n2 = (sq[base] + sq[64 + base]) + (sq[128 + base] + sq[192 + base]);

    const float norm  = sqrtf(n2);
    const float scale = n2 / ((1.f + n2) * (norm + 1e-8f));
    const float v = scale * s;

    if constexpr (MODE == 0) {
        outsum[(size_t)bo * 256 + t] = v;
    } else if constexpr (MODE == 1) {
        outsum[(size_t)bo * 256 + t] += v;
    } else {
        const int bt = bo / NO, o = bo - bt * NO;
        const int b16 = (t >> 2) & 15, hi = t >> 6, q = t & 3;
        dout[((size_t)(bt * BT + b16) * NO + o) * 16 + hi * 4 + q] = v;
    }
}

extern "C" void kernel_launch(void* const* d_in, const int* in_sizes, int n_in,
                              void* d_out, int out_size, void* d_ws, size_t ws_size,
                              hipStream_t stream) {
    const float* x = (const float*)d_in[0];   // [512][1152][8]
    const float* w = (const float*)d_in[1];   // [10][1152][16][8]
    float* out = (float*)d_out;               // [512][10][16]

    float* s_part          = (float*)d_ws;
    float* outsum          = s_part + SPART_F32;
    unsigned short* xb     = (unsigned short*)(outsum + OUTSUM_F32);
    unsigned short* wb     = xb + XB_US;      // total ws ~= 21.2 MB

    cvt_x<<<dim3(2304), dim3(256), 0, stream>>>(x, xb);
    cvt_w<<<dim3(864),  dim3(256), 0, stream>>>(w, wb);

    dim3 gI(NBT * NC), bI(256);               // 768 blocks = 3/CU
    dim3 gS(NBT * NO), bS(256);               // 320 blocks

    caps_iter<true ><<<gI, bI, 0, stream>>>(xb, wb, nullptr, s_part);
    caps_squash<0><<<gS, bS, 0, stream>>>(s_part, outsum, nullptr);
    caps_iter<false><<<gI, bI, 0, stream>>>(xb, wb, outsum, s_part);
    caps_squash<1><<<gS, bS, 0, stream>>>(s_part, outsum, nullptr);
    caps_iter<false><<<gI, bI, 0, stream>>>(xb, wb, outsum, s_part);
    caps_squash<2><<<gS, bS, 0, stream>>>(s_part, nullptr, out);
}

// Round 8
// 77.913 us; speedup vs baseline: 3.2922x; 1.0523x over previous
//
#include <hip/hip_runtime.h>
#include <hip/hip_bf16.h>

#define B_    512
#define NI    1152
#define NO    10
#define BT    16
#define NBT   32           // B_/BT
#define NC    24           // chunks (8 XCD x 3)
#define NCH   48           // n per chunk
#define RNDS  6
#define RN    8            // n per staged round

#define WBUF_US 12288      // W round image: 24 granules * 512 us
#define BUF_US  13312      // + x round image 1024 us

typedef __attribute__((ext_vector_type(8))) short bf16x8;
typedef __attribute__((ext_vector_type(4))) float f32x4;
typedef __attribute__((ext_vector_type(8))) unsigned short u16x8;

// workspace element counts
#define SPART_F32  ((size_t)NC * NBT * NO * 256)      // 1,966,080 f32 (7.86 MB)
#define OUTSUM_F32 ((size_t)NBT * NO * 256)           //    81,920 f32 (0.33 MB)
#define XB_US      ((size_t)NBT * NC * RNDS * 1024)   // 4,718,592 us  (9.44 MB)
#define WB_US      ((size_t)NC * RNDS * WBUF_US)      // 1,769,472 us  (3.54 MB)

__device__ inline unsigned short f2bf(float f) {
    __hip_bfloat16 h = __float2bfloat16(f);
    return *reinterpret_cast<unsigned short*>(&h);
}

__device__ inline void gld_lds16(const void* g, void* lds) {
    __builtin_amdgcn_global_load_lds(
        (const __attribute__((address_space(1))) void*)g,
        (__attribute__((address_space(3))) void*)lds, 16, 0, 0);
}

// Fused conversion. Blocks [0,2304): x -> xb round images; [2304,3168): w -> wb.
// xb image per (bt,nc,r): 1024 us, [nl*128 + bl*8].
// wb image per (nc,r): 12288 us, [(nl*3+oq)*512 + (hi*16+d)*8], o = 4*oq+hi.
__global__ __launch_bounds__(256) void cvt_xw(
    const float* __restrict__ x, const float* __restrict__ w,
    unsigned short* __restrict__ xb, unsigned short* __restrict__ wb)
{
    const int blk = blockIdx.x;
    if (blk < 2304) {
        const int t   = blk * 256 + threadIdx.x;   // 589,824 granules
        const int m   = t & 127;
        const int img = t >> 7;                    // (bt*NC+nc)*6+r
        const int nl  = m >> 4, bl = m & 15;
        const int r   = img % RNDS;
        const int bc  = img / RNDS;
        const int nc  = bc % NC, bt = bc / NC;
        const int b   = bt * BT + bl;
        const int n   = nc * NCH + r * RN + nl;
        const float* src = x + ((size_t)b * NI + n) * 8;
        float4 v0 = *reinterpret_cast<const float4*>(src);
        float4 v1 = *reinterpret_cast<const float4*>(src + 4);
        u16x8 u = { f2bf(v0.x), f2bf(v0.y), f2bf(v0.z), f2bf(v0.w),
                    f2bf(v1.x), f2bf(v1.y), f2bf(v1.z), f2bf(v1.w) };
        *reinterpret_cast<u16x8*>(xb + (size_t)t * 8) = u;
    } else {
        const int t    = (blk - 2304) * 256 + threadIdx.x;  // 221,184 granules
        const int lane = t & 63;
        const int gs   = (t >> 6) % 24;
        const int img  = t / 1536;                 // nc*6+r
        const int hi   = lane >> 4, d = lane & 15;
        const int nl   = gs / 3, oq = gs % 3;
        const int r    = img % RNDS, nc = img / RNDS;
        const int o    = oq * 4 + hi;
        const int n    = nc * NCH + r * RN + nl;
        u16x8 u = {0,0,0,0,0,0,0,0};
        if (o < NO) {
            const float* src = w + ((size_t)o * NI + n) * 128 + d * 8;
            float4 v0 = *reinterpret_cast<const float4*>(src);
            float4 v1 = *reinterpret_cast<const float4*>(src + 4);
            u = (u16x8){ f2bf(v0.x), f2bf(v0.y), f2bf(v0.z), f2bf(v0.w),
                         f2bf(v1.x), f2bf(v1.y), f2bf(v1.z), f2bf(v1.w) };
        }
        *reinterpret_cast<u16x8*>(wb + (size_t)t * 8) = u;
    }
}

// One routing iteration. Block = bt x nc; 6 double-buffered rounds of 8 n.
// Round r+1's global_load_lds batch is issued BEFORE round r's compute, so
// the vmcnt(0) drain at round end is covered by compute (T3-lite).
template<bool UNIFORM>
__global__ __launch_bounds__(256, 3) void caps_iter(
    const unsigned short* __restrict__ xb,
    const unsigned short* __restrict__ wb,
    const float* __restrict__ outsum,    // [bt*10+o][64][4] lane-major f32
    float* __restrict__ s_part)          // [nc][bt][o][64][4] f32
{
    __shared__ unsigned short lds[2 * BUF_US];   // 53,248 B -> 3 blocks/CU

    const int tid = threadIdx.x;
    const int w   = tid >> 6;
    const int l   = tid & 63;
    const int b16 = l & 15;
    const int hi  = l >> 4;
    const int blk = blockIdx.x;
    const int xcd = blk & 7, idx = blk >> 3;     // XCD owns 3 chunks
    const int nc  = xcd * 3 + (idx >> 5);
    const int bt  = idx & 31;

    const unsigned short* wsrc = wb + (size_t)nc * (RNDS * WBUF_US);
    const unsigned short* xsrc = xb + ((size_t)bt * NC + nc) * (RNDS * 1024);

    auto stage = [&](int r, int kbuf) {
        const unsigned short* wr = wsrc + (size_t)r * WBUF_US;
        char* dst = (char*)lds + kbuf * (BUF_US * 2);
        #pragma unroll
        for (int k = 0; k < 6; ++k)          // 1536 16B chunks of W
            gld_lds16(wr + (k * 256 + tid) * 8, dst + (k * 256 + tid) * 16);
        if (tid < 128)                       // 128 16B chunks of x
            gld_lds16(xsrc + (size_t)r * 1024 + tid * 8,
                      dst + WBUF_US * 2 + tid * 16);
    };

    f32x4 outf[NO];
    if constexpr (!UNIFORM) {
        #pragma unroll
        for (int o = 0; o < NO; ++o)
            outf[o] = *reinterpret_cast<const f32x4*>(
                outsum + (((size_t)bt * NO + o) * 64 + l) * 4);
    }

    f32x4 sacc[NO];
    #pragma unroll
    for (int o = 0; o < NO; ++o) sacc[o] = (f32x4){0.f, 0.f, 0.f, 0.f};

    stage(0, 0);
    asm volatile("s_waitcnt vmcnt(0)" ::: "memory");
    __syncthreads();

    #pragma unroll 1
    for (int r = 0; r < RNDS; ++r) {
        if (r + 1 < RNDS) stage(r + 1, (r + 1) & 1);   // prefetch next round

        const int ub = (r & 1) * BUF_US;               // this round's buffer

        #pragma unroll 1
        for (int i = 0; i < 2; ++i) {
            const int nl = w * 2 + i;                  // wave's n within round
            bf16x8 bv = *reinterpret_cast<const bf16x8*>(
                &lds[ub + WBUF_US + nl * 128 + b16 * 8]);
            bf16x8 bvt[4];
            #pragma unroll
            for (int t = 0; t < 4; ++t)
                bvt[t] = (hi == t) ? bv : (bf16x8){0,0,0,0,0,0,0,0};

            if constexpr (UNIFORM) {
                #pragma unroll
                for (int oq = 0; oq < 3; ++oq) {
                    bf16x8 av = *reinterpret_cast<const bf16x8*>(
                        &lds[ub + (nl * 3 + oq) * 512 + l * 8]);
                    const int tmax = (oq < 2) ? 4 : 2;
                    #pragma unroll
                    for (int t = 0; t < tmax; ++t)
                        sacc[oq * 4 + t] = __builtin_amdgcn_mfma_f32_16x16x32_bf16(
                            av, bvt[t], sacc[oq * 4 + t], 0, 0, 0);
                }
            } else {
                float lg[NO];
                #pragma unroll
                for (int oq = 0; oq < 3; ++oq) {
                    bf16x8 av = *reinterpret_cast<const bf16x8*>(
                        &lds[ub + (nl * 3 + oq) * 512 + l * 8]);
                    const int tmax = (oq < 2) ? 4 : 2;
                    #pragma unroll
                    for (int t = 0; t < tmax; ++t) {
                        f32x4 xh = __builtin_amdgcn_mfma_f32_16x16x32_bf16(
                            av, bvt[t], (f32x4){0.f, 0.f, 0.f, 0.f}, 0, 0, 0);
                        const int o = oq * 4 + t;
                        float pp = outf[o][0] * xh[0];
                        pp = fmaf(outf[o][1], xh[1], pp);
                        pp = fmaf(outf[o][2], xh[2], pp);
                        pp = fmaf(outf[o][3], xh[3], pp);
                        pp += __shfl_xor(pp, 16, 64);
                        pp += __shfl_xor(pp, 32, 64);
                        lg[o] = pp;
                    }
                }
                float sum = 0.f;
                #pragma unroll
                for (int o = 0; o < NO; ++o) { lg[o] = __expf(lg[o]); sum += lg[o]; }
                const float rs = __builtin_amdgcn_rcpf(sum);
                #pragma unroll
                for (int oq = 0; oq < 3; ++oq) {
                    bf16x8 av = *reinterpret_cast<const bf16x8*>(
                        &lds[ub + (nl * 3 + oq) * 512 + l * 8]);
                    const int tmax = (oq < 2) ? 4 : 2;
                    #pragma unroll
                    for (int t = 0; t < tmax; ++t) {
                        f32x4 xh = __builtin_amdgcn_mfma_f32_16x16x32_bf16(
                            av, bvt[t], (f32x4){0.f, 0.f, 0.f, 0.f}, 0, 0, 0);
                        const int o = oq * 4 + t;
                        const float cc = lg[o] * rs;
                        sacc[o][0] = fmaf(cc, xh[0], sacc[o][0]);
                        sacc[o][1] = fmaf(cc, xh[1], sacc[o][1]);
                        sacc[o][2] = fmaf(cc, xh[2], sacc[o][2]);
                        sacc[o][3] = fmaf(cc, xh[3], sacc[o][3]);
                    }
                }
            }
        }

        // prefetched loads have had a full round of compute to land
        asm volatile("s_waitcnt vmcnt(0)" ::: "memory");
        __syncthreads();
    }

    // cross-wave reduce via lane-major LDS (conflict-free), coalesced store
    const float sc = UNIFORM ? 0.1f : 1.0f;
    f32x4* red = reinterpret_cast<f32x4*>(lds);
    #pragma unroll
    for (int o = 0; o < NO; ++o)
        red[w * 640 + o * 64 + l] =
            (f32x4){sacc[o][0] * sc, sacc[o][1] * sc,
                    sacc[o][2] * sc, sacc[o][3] * sc};
    __syncthreads();
    float* base = s_part + ((size_t)nc * NBT + bt) * 2560;
    for (int g = tid; g < 640; g += 256) {
        f32x4 a0 = red[g], a1 = red[640 + g], a2 = red[1280 + g], a3 = red[1920 + g];
        f32x4 s;
        #pragma unroll
        for (int q = 0; q < 4; ++q) s[q] = (a0[q] + a1[q]) + (a2[q] + a3[q]);
        *reinterpret_cast<f32x4*>(base + (size_t)g * 4) = s;
    }
}

// Reduce chunks + squash. Block bo = bt*10+o; thread t: l=t>>2, q=t&3.
template<int MODE>
__global__ __launch_bounds__(256) void caps_squash(
    const float* __restrict__ s_part,
    float* __restrict__ outsum,
    float* __restrict__ dout)
{
    __shared__ float sq[256];
    const int bo = blockIdx.x;
    const int t  = threadIdx.x;

    float s = 0.f;
    #pragma unroll
    for (int nc = 0; nc < NC; ++nc)
        s += s_part[((size_t)nc * NBT * NO + bo) * 256 + t];

    float n2 = s * s;
    n2 += __shfl_xor(n2, 1, 64);
    n2 += __shfl_xor(n2, 2, 64);       // q-pair reduced
    sq[t] = n2;
    __syncthreads();
    const int base = t & 63;
    n2 = (sq[base] + sq[64 + base]) + (sq[128 + base] + sq[192 + base]);

    const float norm  = sqrtf(n2);
    const float scale = n2 / ((1.f + n2) * (norm + 1e-8f));
    const float v = scale * s;

    if constexpr (MODE == 0) {
        outsum[(size_t)bo * 256 + t] = v;
    } else if constexpr (MODE == 1) {
        outsum[(size_t)bo * 256 + t] += v;
    } else {
        const int bt = bo / NO, o = bo - bt * NO;
        const int b16 = (t >> 2) & 15, hi = t >> 6, q = t & 3;
        dout[((size_t)(bt * BT + b16) * NO + o) * 16 + hi * 4 + q] = v;
    }
}

extern "C" void kernel_launch(void* const* d_in, const int* in_sizes, int n_in,
                              void* d_out, int out_size, void* d_ws, size_t ws_size,
                              hipStream_t stream) {
    const float* x = (const float*)d_in[0];   // [512][1152][8]
    const float* w = (const float*)d_in[1];   // [10][1152][16][8]
    float* out = (float*)d_out;               // [512][10][16]

    float* s_part          = (float*)d_ws;
    float* outsum          = s_part + SPART_F32;
    unsigned short* xb     = (unsigned short*)(outsum + OUTSUM_F32);
    unsigned short* wb     = xb + XB_US;      // total ws ~= 21.2 MB

    cvt_xw<<<dim3(3168), dim3(256), 0, stream>>>(x, w, xb, wb);

    dim3 gI(NBT * NC), bI(256);               // 768 blocks = 3/CU
    dim3 gS(NBT * NO), bS(256);               // 320 blocks

    caps_iter<true ><<<gI, bI, 0, stream>>>(xb, wb, nullptr, s_part);
    caps_squash<0><<<gS, bS, 0, stream>>>(s_part, outsum, nullptr);
    caps_iter<false><<<gI, bI, 0, stream>>>(xb, wb, outsum, s_part);
    caps_squash<1><<<gS, bS, 0, stream>>>(s_part, outsum, nullptr);
    caps_iter<false><<<gI, bI, 0, stream>>>(xb, wb, outsum, s_part);
    caps_squash<2><<<gS, bS, 0, stream>>>(s_part, nullptr, out);
}